// Round 4
// baseline (89.258 us; speedup 1.0000x reference)
//
#include <hip/hip_runtime.h>
#include <hip/hip_bf16.h>
#include <math.h>

#define N_RAYS  32768
#define M_GAUSS 1024

typedef short v8s __attribute__((ext_vector_type(8)));
typedef float v4f __attribute__((ext_vector_type(4)));

__device__ __forceinline__ float fexp2(float x) {
#if __has_builtin(__builtin_amdgcn_exp2f)
    return __builtin_amdgcn_exp2f(x);
#else
    return exp2f(x);
#endif
}

union BFU { __hip_bfloat16 b; unsigned short u; };
__device__ __forceinline__ unsigned short f2bf(float f) { BFU x; x.b = __float2bfloat16(f); return x.u; }
__device__ __forceinline__ float bf2f(unsigned short u)  { BFU x; x.u = u; return __bfloat162float(x.b); }

// split f = hi + lo with hi,lo bf16; f - float(hi) is exact in fp32
__device__ __forceinline__ void split_bf16(float f, unsigned short& hi, unsigned short& lo) {
    hi = f2bf(f);
    lo = f2bf(f - bf2f(hi));
}

__device__ __forceinline__ void store8(unsigned short* dst, const unsigned short* s) {
    uint4 v;
    v.x = (unsigned)s[0] | ((unsigned)s[1] << 16);
    v.y = (unsigned)s[2] | ((unsigned)s[3] << 16);
    v.z = (unsigned)s[4] | ((unsigned)s[5] << 16);
    v.w = (unsigned)s[6] | ((unsigned)s[7] << 16);
    *reinterpret_cast<uint4*>(dst) = v;
}

// ---------------------------------------------------------------------------
// Prep (one kernel, 32768 threads):
//  * every thread n: 15 monomial features of ray n, split hi/lo, write the
//    A-fragment table F_swz[row-tile][lane][8 bf16] (MFMA A layout:
//    A[m=lane&15][k=quad*8+j]; k0-15 = f_hi, k16-31 = f_lo).
//  * threads n<1024: fp32 adjugate inverse of covariance n -> 15 coeffs with
//    k=-0.5*log2(e) folded in, split hi/lo, write compact B tables
//    (quads 0,1 only; decoder folds quads 2,3 by L&31):
//      B1c = w_hi (used for k0-15 AND k16-31  => w_hi*(f_hi+f_lo))
//      B2c = w_lo (k0-15 only; k16-31 zeroed by lane mask => w_lo*f_hi)
// ---------------------------------------------------------------------------
__global__ __launch_bounds__(256) void prep_kernel(
    const float2* __restrict__ org,   // [N]
    const float2* __restrict__ dir,   // [N]
    const float*  __restrict__ means, // [M,4]
    const float*  __restrict__ covs,  // [M,4,4]
    unsigned short* __restrict__ Fs,  // [2048][64][8] bf16 = 2 MB
    unsigned short* __restrict__ Bt)  // [64 KB]: B1c (32 KB) || B2c (32 KB)
{
    const int n = blockIdx.x * 256 + threadIdx.x;

    // ---- features ----
    {
        const float2 o = org[n];
        const float2 d = dir[n];
        const float p0 = o.x, p1 = o.y, p2 = d.x, p3 = d.y;
        float f[16] = { p0*p0, p1*p1, p2*p2, p3*p3,
                        p0*p1, p0*p2, p0*p3, p1*p2, p1*p3, p2*p3,
                        p0, p1, p2, p3, 1.0f, 0.0f };
        unsigned short hi[16], lo[16];
        #pragma unroll
        for (int k = 0; k < 16; ++k) split_bf16(f[k], hi[k], lo[k]);

        const int rt = n >> 4, c = n & 15;
        unsigned short* base = Fs + (size_t)rt * 64 * 8;
        store8(base + (0*16 + c) * 8, hi + 0);   // quad 0: f_hi k0-7
        store8(base + (1*16 + c) * 8, hi + 8);   // quad 1: f_hi k8-15
        store8(base + (2*16 + c) * 8, lo + 0);   // quad 2: f_lo k0-7
        store8(base + (3*16 + c) * 8, lo + 8);   // quad 3: f_lo k8-15
    }

    // ---- gaussian coefficients ----
    if (n < M_GAUSS) {
        const int g = n;
        const float4* C4 = reinterpret_cast<const float4*>(covs + 16 * g);
        const float4 r0 = C4[0], r1 = C4[1], r2 = C4[2], r3 = C4[3];
        const float a00=r0.x, a01=r0.y, a02=r0.z, a03=r0.w;
        const float a10=r1.x, a11=r1.y, a12=r1.z, a13=r1.w;
        const float a20=r2.x, a21=r2.y, a22=r2.z, a23=r2.w;
        const float a30=r3.x, a31=r3.y, a32=r3.z, a33=r3.w;

        const float s0=a00*a11-a01*a10, s1=a00*a12-a02*a10, s2=a00*a13-a03*a10;
        const float s3=a01*a12-a02*a11, s4=a01*a13-a03*a11, s5=a02*a13-a03*a12;
        const float c5=a22*a33-a23*a32, c4=a21*a33-a23*a31, c3=a21*a32-a22*a31;
        const float c2=a20*a33-a23*a30, c1=a20*a32-a22*a30, c0=a20*a31-a21*a30;
        const float det = s0*c5 - s1*c4 + s2*c3 + s3*c2 - s4*c1 + s5*c0;
        const float id  = 1.0f / det;

        const float b00=( a11*c5 - a12*c4 + a13*c3)*id;
        const float b01=(-a01*c5 + a02*c4 - a03*c3)*id;
        const float b10=(-a10*c5 + a12*c2 - a13*c1)*id;
        const float b11=( a00*c5 - a02*c2 + a03*c1)*id;
        const float b20=( a10*c4 - a11*c2 + a13*c0)*id;
        const float b21=(-a00*c4 + a01*c2 - a03*c0)*id;
        const float b30=(-a10*c3 + a11*c1 - a12*c0)*id;
        const float b31=( a00*c3 - a01*c1 + a02*c0)*id;
        const float b02=( a31*s5 - a32*s4 + a33*s3)*id;
        const float b03=(-a21*s5 + a22*s4 - a23*s3)*id;
        const float b12=(-a30*s5 + a32*s2 - a33*s1)*id;
        const float b13=( a20*s5 - a22*s2 + a23*s1)*id;
        const float b22=( a30*s4 - a31*s2 + a33*s0)*id;
        const float b23=(-a20*s4 + a21*s2 - a23*s0)*id;
        const float b32=(-a30*s3 + a31*s1 - a32*s0)*id;
        const float b33=( a20*s3 - a21*s1 + a22*s0)*id;

        const float m01=0.5f*(b01+b10), m02=0.5f*(b02+b20), m03=0.5f*(b03+b30);
        const float m12=0.5f*(b12+b21), m13=0.5f*(b13+b31), m23=0.5f*(b23+b32);

        const float4 mu = reinterpret_cast<const float4*>(means)[g];
        const float u0=mu.x, u1=mu.y, u2=mu.z, u3=mu.w;
        const float v0 = b00*u0 + m01*u1 + m02*u2 + m03*u3;
        const float v1 = m01*u0 + b11*u1 + m12*u2 + m13*u3;
        const float v2 = m02*u0 + m12*u1 + b22*u2 + m23*u3;
        const float v3 = m03*u0 + m13*u1 + m23*u2 + b33*u3;
        const float cc = u0*v0 + u1*v1 + u2*v2 + u3*v3;

        const float k  = -0.72134752044448170368f;   // -0.5 * log2(e)
        const float k2 = 2.0f * k;
        float w[16] = { k*b00,  k*b11,  k*b22,  k*b33,
                        k2*m01, k2*m02, k2*m03, k2*m12, k2*m13, k2*m23,
                        -k2*v0, -k2*v1, -k2*v2, -k2*v3, k*cc, 0.0f };
        unsigned short whi[16], wlo[16];
        #pragma unroll
        for (int q = 0; q < 16; ++q) split_bf16(w[q], whi[q], wlo[q]);

        const int t = g >> 4, cg = g & 15;
        unsigned short* b1 = Bt + (size_t)t * 32 * 8;            // B1c tile
        store8(b1 + (0*16 + cg) * 8, whi + 0);   // quad 0: w_hi k0-7
        store8(b1 + (1*16 + cg) * 8, whi + 8);   // quad 1: w_hi k8-15
        unsigned short* b2 = Bt + (size_t)2048 * 8 + (size_t)t * 32 * 8;   // B2c tile
        store8(b2 + (0*16 + cg) * 8, wlo + 0);
        store8(b2 + (1*16 + cg) * 8, wlo + 8);
    }
}

// ---------------------------------------------------------------------------
// Decoder. 512 blocks x 512 threads (8 waves); block owns 64 rays
// (4 MFMA row-tiles), wave w sweeps gaussian tiles [8w, 8w+8).
// B tables (64 KB compact) staged to LDS once; per-tile B frags are
// 2-lane-broadcast ds_read_b128 (free). Two MFMAs per row-tile per m-tile
// (split-bf16), then epilogue: acc += label * exp2(s). Cross-wave combine
// via LDS float atomics into P[64][17] (aliased onto the dead B region).
// 2 blocks/CU (128 KB LDS) -> 32 waves/CU.
// ---------------------------------------------------------------------------
__global__ __launch_bounds__(512) void decoder_kernel(
    const uint4* __restrict__ Fs,      // A-frag table
    const uint4* __restrict__ Btg,     // 64 KB B tables (B1c || B2c)
    const float* __restrict__ labels,  // [M]
    float*       __restrict__ out)     // [N]
{
    __shared__ uint4 lds[4096];        // 64 KB: B1c [0,2048) | B2c [2048,4096)

    const int tid = threadIdx.x;
    const int L   = tid & 63;
    const int w   = tid >> 6;
    const int c15 = L & 15;
    const int q   = L >> 4;

    // stage B tables (linear copy, coalesced)
    #pragma unroll
    for (int i = 0; i < 8; ++i) lds[i * 512 + tid] = Btg[i * 512 + tid];

    // A fragments: 4 row-tiles (64 rays) per block, held in registers
    const int rt0 = blockIdx.x * 4;
    v8s af[4];
    #pragma unroll
    for (int rt = 0; rt < 4; ++rt) {
        union { uint4 u; v8s s; } x;
        x.u = Fs[(size_t)(rt0 + rt) * 64 + L];
        af[rt] = x.s;
    }
    __syncthreads();

    v4f acc[4];
    #pragma unroll
    for (int rt = 0; rt < 4; ++rt) acc[rt] = (v4f){0.f, 0.f, 0.f, 0.f};

    const bool loHalf = (L < 32);
    #pragma unroll 2
    for (int i = 0; i < 8; ++i) {
        const int t = w * 8 + i;
        union { uint4 u; v8s s; } b1x, b2x;
        b1x.u = lds[t * 32 + (L & 31)];
        uint4 b2u = lds[2048 + t * 32 + (L & 31)];
        if (!loHalf) { b2u.x = 0; b2u.y = 0; b2u.z = 0; b2u.w = 0; }  // [w_lo | 0]
        b2x.u = b2u;
        const float lab = labels[t * 16 + c15];

        #pragma unroll
        for (int rt = 0; rt < 4; ++rt) {
            v4f cz = (v4f){0.f, 0.f, 0.f, 0.f};
            v4f s = __builtin_amdgcn_mfma_f32_16x16x32_bf16(af[rt], b2x.s, cz, 0, 0, 0);
            s = __builtin_amdgcn_mfma_f32_16x16x32_bf16(af[rt], b1x.s, s, 0, 0, 0);
            #pragma unroll
            for (int r = 0; r < 4; ++r)
                acc[rt][r] = fmaf(lab, fexp2(s[r]), acc[rt][r]);
        }
    }

    // ---- cross-wave combine: P[ray][col] with +1 pad, atomic adds ----
    __syncthreads();                       // all B reads done; LDS reusable
    float* P = reinterpret_cast<float*>(lds);
    for (int i = tid; i < 64 * 17; i += 512) P[i] = 0.f;
    __syncthreads();
    #pragma unroll
    for (int rt = 0; rt < 4; ++rt) {
        #pragma unroll
        for (int r = 0; r < 4; ++r) {
            const int ray = rt * 16 + q * 4 + r;   // D row = quad*4 + reg
            atomicAdd(&P[ray * 17 + c15], acc[rt][r]);
        }
    }
    __syncthreads();

    if (tid < 64) {
        float tsum = 0.f;
        #pragma unroll
        for (int c = 0; c < 16; ++c) tsum += P[tid * 17 + c];
        const float e = fexp2(-tsum * 1.4426950408889634f);
        out[blockIdx.x * 64 + tid] = 1.0f / (1.0f + e);
    }
}

extern "C" void kernel_launch(void* const* d_in, const int* in_sizes, int n_in,
                              void* d_out, int out_size, void* d_ws, size_t ws_size,
                              hipStream_t stream) {
    const float* origins    = (const float*)d_in[0];  // [N,2]
    const float* directions = (const float*)d_in[1];  // [N,2]
    const float* means      = (const float*)d_in[2];  // [M,4]
    const float* covs       = (const float*)d_in[3];  // [M,4,4]
    const float* labels     = (const float*)d_in[4];  // [M]
    float* out = (float*)d_out;

    char* ws = (char*)d_ws;
    unsigned short* Fs = (unsigned short*)ws;                    // 2 MB A-frag table
    unsigned short* Bt = (unsigned short*)(ws + (size_t)2 * 1024 * 1024); // 64 KB B tables

    prep_kernel<<<dim3(N_RAYS / 256), dim3(256), 0, stream>>>(
        (const float2*)origins, (const float2*)directions, means, covs, Fs, Bt);
    decoder_kernel<<<dim3(N_RAYS / 64), dim3(512), 0, stream>>>(
        (const uint4*)Fs, (const uint4*)Bt, labels, out);
}

// Round 6
// 70.564 us; speedup vs baseline: 1.2649x; 1.2649x over previous
//
#include <hip/hip_runtime.h>
#include <hip/hip_bf16.h>
#include <math.h>

#define N_RAYS  32768
#define M_GAUSS 1024

typedef short v8s __attribute__((ext_vector_type(8)));
typedef float v4f __attribute__((ext_vector_type(4)));

__device__ __forceinline__ float fexp2(float x) {
#if __has_builtin(__builtin_amdgcn_exp2f)
    return __builtin_amdgcn_exp2f(x);
#else
    return exp2f(x);
#endif
}

union BFU { __hip_bfloat16 b; unsigned short u; };
__device__ __forceinline__ unsigned short f2bf(float f) { BFU x; x.b = __float2bfloat16(f); return x.u; }
__device__ __forceinline__ float bf2f(unsigned short u)  { BFU x; x.u = u; return __bfloat162float(x.b); }

// split f = hi + lo with hi,lo bf16; f - float(hi) is exact in fp32
__device__ __forceinline__ void split_bf16(float f, unsigned short& hi, unsigned short& lo) {
    hi = f2bf(f);
    lo = f2bf(f - bf2f(hi));
}

__device__ __forceinline__ void store8(unsigned short* dst, const unsigned short* s) {
    uint4 v;
    v.x = (unsigned)s[0] | ((unsigned)s[1] << 16);
    v.y = (unsigned)s[2] | ((unsigned)s[3] << 16);
    v.z = (unsigned)s[4] | ((unsigned)s[5] << 16);
    v.w = (unsigned)s[6] | ((unsigned)s[7] << 16);
    *reinterpret_cast<uint4*>(dst) = v;
}

// ---------------------------------------------------------------------------
// Prep (identical to the R4 kernel that passed):
//  * every thread n: 15 monomial features of ray n, split hi/lo, write the
//    A-fragment table F_swz[row-tile][lane][8 bf16] (MFMA A layout:
//    A[m=lane&15][k=quad*8+j]; k0-15 = f_hi, k16-31 = f_lo).
//  * threads n<1024: fp32 adjugate inverse of covariance n -> 15 coeffs with
//    k=-0.5*log2(e) folded in, split hi/lo, write compact B tables:
//      B1c = w_hi (decoder replicates to k16-31 => w_hi*(f_hi+f_lo))
//      B2c = w_lo (decoder zeroes k16-31      => w_lo*f_hi)
// ---------------------------------------------------------------------------
__global__ __launch_bounds__(256) void prep_kernel(
    const float2* __restrict__ org,   // [N]
    const float2* __restrict__ dir,   // [N]
    const float*  __restrict__ means, // [M,4]
    const float*  __restrict__ covs,  // [M,4,4]
    unsigned short* __restrict__ Fs,  // [2048][64][8] bf16 = 2 MB
    unsigned short* __restrict__ Bt)  // [64 KB]: B1c (32 KB) || B2c (32 KB)
{
    const int n = blockIdx.x * 256 + threadIdx.x;

    // ---- features ----
    {
        const float2 o = org[n];
        const float2 d = dir[n];
        const float p0 = o.x, p1 = o.y, p2 = d.x, p3 = d.y;
        float f[16] = { p0*p0, p1*p1, p2*p2, p3*p3,
                        p0*p1, p0*p2, p0*p3, p1*p2, p1*p3, p2*p3,
                        p0, p1, p2, p3, 1.0f, 0.0f };
        unsigned short hi[16], lo[16];
        #pragma unroll
        for (int k = 0; k < 16; ++k) split_bf16(f[k], hi[k], lo[k]);

        const int rt = n >> 4, c = n & 15;
        unsigned short* base = Fs + (size_t)rt * 64 * 8;
        store8(base + (0*16 + c) * 8, hi + 0);   // quad 0: f_hi k0-7
        store8(base + (1*16 + c) * 8, hi + 8);   // quad 1: f_hi k8-15
        store8(base + (2*16 + c) * 8, lo + 0);   // quad 2: f_lo k0-7
        store8(base + (3*16 + c) * 8, lo + 8);   // quad 3: f_lo k8-15
    }

    // ---- gaussian coefficients ----
    if (n < M_GAUSS) {
        const int g = n;
        const float4* C4 = reinterpret_cast<const float4*>(covs + 16 * g);
        const float4 r0 = C4[0], r1 = C4[1], r2 = C4[2], r3 = C4[3];
        const float a00=r0.x, a01=r0.y, a02=r0.z, a03=r0.w;
        const float a10=r1.x, a11=r1.y, a12=r1.z, a13=r1.w;
        const float a20=r2.x, a21=r2.y, a22=r2.z, a23=r2.w;
        const float a30=r3.x, a31=r3.y, a32=r3.z, a33=r3.w;

        const float s0=a00*a11-a01*a10, s1=a00*a12-a02*a10, s2=a00*a13-a03*a10;
        const float s3=a01*a12-a02*a11, s4=a01*a13-a03*a11, s5=a02*a13-a03*a12;
        const float c5=a22*a33-a23*a32, c4=a21*a33-a23*a31, c3=a21*a32-a22*a31;
        const float c2=a20*a33-a23*a30, c1=a20*a32-a22*a30, c0=a20*a31-a21*a30;
        const float det = s0*c5 - s1*c4 + s2*c3 + s3*c2 - s4*c1 + s5*c0;
        const float id  = 1.0f / det;

        const float b00=( a11*c5 - a12*c4 + a13*c3)*id;
        const float b01=(-a01*c5 + a02*c4 - a03*c3)*id;
        const float b10=(-a10*c5 + a12*c2 - a13*c1)*id;
        const float b11=( a00*c5 - a02*c2 + a03*c1)*id;
        const float b20=( a10*c4 - a11*c2 + a13*c0)*id;
        const float b21=(-a00*c4 + a01*c2 - a03*c0)*id;
        const float b30=(-a10*c3 + a11*c1 - a12*c0)*id;
        const float b31=( a00*c3 - a01*c1 + a02*c0)*id;
        const float b02=( a31*s5 - a32*s4 + a33*s3)*id;
        const float b03=(-a21*s5 + a22*s4 - a23*s3)*id;
        const float b12=(-a30*s5 + a32*s2 - a33*s1)*id;
        const float b13=( a20*s5 - a22*s2 + a23*s1)*id;
        const float b22=( a30*s4 - a31*s2 + a33*s0)*id;
        const float b23=(-a20*s4 + a21*s2 - a23*s0)*id;
        const float b32=(-a30*s3 + a31*s1 - a32*s0)*id;
        const float b33=( a20*s3 - a21*s1 + a22*s0)*id;

        const float m01=0.5f*(b01+b10), m02=0.5f*(b02+b20), m03=0.5f*(b03+b30);
        const float m12=0.5f*(b12+b21), m13=0.5f*(b13+b31), m23=0.5f*(b23+b32);

        const float4 mu = reinterpret_cast<const float4*>(means)[g];
        const float u0=mu.x, u1=mu.y, u2=mu.z, u3=mu.w;
        const float v0 = b00*u0 + m01*u1 + m02*u2 + m03*u3;
        const float v1 = m01*u0 + b11*u1 + m12*u2 + m13*u3;
        const float v2 = m02*u0 + m12*u1 + b22*u2 + m23*u3;
        const float v3 = m03*u0 + m13*u1 + m23*u2 + b33*u3;
        const float cc = u0*v0 + u1*v1 + u2*v2 + u3*v3;

        const float k  = -0.72134752044448170368f;   // -0.5 * log2(e)
        const float k2 = 2.0f * k;
        float w[16] = { k*b00,  k*b11,  k*b22,  k*b33,
                        k2*m01, k2*m02, k2*m03, k2*m12, k2*m13, k2*m23,
                        -k2*v0, -k2*v1, -k2*v2, -k2*v3, k*cc, 0.0f };
        unsigned short whi[16], wlo[16];
        #pragma unroll
        for (int q = 0; q < 16; ++q) split_bf16(w[q], whi[q], wlo[q]);

        const int t = g >> 4, cg = g & 15;
        unsigned short* b1 = Bt + (size_t)t * 32 * 8;            // B1c tile
        store8(b1 + (0*16 + cg) * 8, whi + 0);   // quad 0: w_hi k0-7
        store8(b1 + (1*16 + cg) * 8, whi + 8);   // quad 1: w_hi k8-15
        unsigned short* b2 = Bt + (size_t)2048 * 8 + (size_t)t * 32 * 8;   // B2c tile
        store8(b2 + (0*16 + cg) * 8, wlo + 0);
        store8(b2 + (1*16 + cg) * 8, wlo + 8);
    }
}

// ---------------------------------------------------------------------------
// Decoder (R4 structure, passed at absmax 0.0039): 512 blocks x 512 threads
// (8 waves); block owns 64 rays (4 MFMA row-tiles), wave w sweeps gaussian
// tiles [8w, 8w+8). B tables (64 KB) staged to LDS once; per-tile B frags are
// 2-lane-broadcast ds_read_b128. Two MFMAs per row-tile per m-tile
// (split-bf16), epilogue acc += label*exp2(s).
// ONLY delta vs R4: cross-wave combine uses disjoint per-wave LDS regions
// P[8][64][16] (32 KB, aliased onto the dead B region) instead of 8-way
// contended LDS atomicAdds; and the tile loop is fully unrolled.
// ---------------------------------------------------------------------------
__global__ __launch_bounds__(512) void decoder_kernel(
    const uint4* __restrict__ Fs,      // A-frag table
    const uint4* __restrict__ Btg,     // 64 KB B tables (B1c || B2c)
    const float* __restrict__ labels,  // [M]
    float*       __restrict__ out)     // [N]
{
    __shared__ uint4 lds[4096];        // 64 KB: B1c [0,2048) | B2c [2048,4096)

    const int tid = threadIdx.x;
    const int L   = tid & 63;
    const int w   = tid >> 6;
    const int c15 = L & 15;
    const int q   = L >> 4;

    // stage B tables (linear copy, coalesced)
    #pragma unroll
    for (int i = 0; i < 8; ++i) lds[i * 512 + tid] = Btg[i * 512 + tid];

    // A fragments: 4 row-tiles (64 rays) per block, held in registers
    const int rt0 = blockIdx.x * 4;
    v8s af[4];
    #pragma unroll
    for (int rt = 0; rt < 4; ++rt) {
        union { uint4 u; v8s s; } x;
        x.u = Fs[(size_t)(rt0 + rt) * 64 + L];
        af[rt] = x.s;
    }
    __syncthreads();

    v4f acc[4];
    #pragma unroll
    for (int rt = 0; rt < 4; ++rt) acc[rt] = (v4f){0.f, 0.f, 0.f, 0.f};

    const bool loHalf = (L < 32);
    #pragma unroll
    for (int i = 0; i < 8; ++i) {
        const int t = w * 8 + i;
        union { uint4 u; v8s s; } b1x, b2x;
        b1x.u = lds[t * 32 + (L & 31)];                 // [w_hi | w_hi]
        uint4 b2u = lds[2048 + t * 32 + (L & 31)];
        if (!loHalf) { b2u.x = 0; b2u.y = 0; b2u.z = 0; b2u.w = 0; }  // [w_lo | 0]
        b2x.u = b2u;
        const float lab = labels[t * 16 + c15];

        #pragma unroll
        for (int rt = 0; rt < 4; ++rt) {
            v4f cz = (v4f){0.f, 0.f, 0.f, 0.f};
            v4f s = __builtin_amdgcn_mfma_f32_16x16x32_bf16(af[rt], b2x.s, cz, 0, 0, 0);
            s = __builtin_amdgcn_mfma_f32_16x16x32_bf16(af[rt], b1x.s, s, 0, 0, 0);
            #pragma unroll
            for (int r = 0; r < 4; ++r)
                acc[rt][r] = fmaf(lab, fexp2(s[r]), acc[rt][r]);
        }
    }

    // ---- cross-wave combine: disjoint P[wave][ray][col], no atomics ----
    __syncthreads();                       // all B reads done; LDS reusable
    float* P = reinterpret_cast<float*>(lds);   // [8][64][16] = 32 KB
    #pragma unroll
    for (int rt = 0; rt < 4; ++rt) {
        #pragma unroll
        for (int r = 0; r < 4; ++r) {
            const int ray = rt * 16 + q * 4 + r;   // D row = quad*4 + reg
            P[(w << 10) + (ray << 4) + c15] = acc[rt][r];
        }
    }
    __syncthreads();

    if (tid < 64) {
        float tsum = 0.f;
        #pragma unroll
        for (int wv = 0; wv < 8; ++wv) {
            const float4* row = reinterpret_cast<const float4*>(P + (wv << 10) + (tid << 4));
            #pragma unroll
            for (int c4 = 0; c4 < 4; ++c4) {
                const float4 v = row[c4];
                tsum += (v.x + v.y) + (v.z + v.w);
            }
        }
        const float e = fexp2(-tsum * 1.4426950408889634f);
        out[blockIdx.x * 64 + tid] = 1.0f / (1.0f + e);
    }
}

extern "C" void kernel_launch(void* const* d_in, const int* in_sizes, int n_in,
                              void* d_out, int out_size, void* d_ws, size_t ws_size,
                              hipStream_t stream) {
    const float* origins    = (const float*)d_in[0];  // [N,2]
    const float* directions = (const float*)d_in[1];  // [N,2]
    const float* means      = (const float*)d_in[2];  // [M,4]
    const float* covs       = (const float*)d_in[3];  // [M,4,4]
    const float* labels     = (const float*)d_in[4];  // [M]
    float* out = (float*)d_out;

    char* ws = (char*)d_ws;
    unsigned short* Fs = (unsigned short*)ws;                    // 2 MB A-frag table
    unsigned short* Bt = (unsigned short*)(ws + (size_t)2 * 1024 * 1024); // 64 KB B tables

    prep_kernel<<<dim3(N_RAYS / 256), dim3(256), 0, stream>>>(
        (const float2*)origins, (const float2*)directions, means, covs, Fs, Bt);
    decoder_kernel<<<dim3(N_RAYS / 64), dim3(512), 0, stream>>>(
        (const uint4*)Fs, (const uint4*)Bt, labels, out);
}

// Round 7
// 69.897 us; speedup vs baseline: 1.2770x; 1.0095x over previous
//
#include <hip/hip_runtime.h>
#include <hip/hip_bf16.h>
#include <math.h>

#define N_RAYS  32768
#define M_GAUSS 1024

typedef short v8s __attribute__((ext_vector_type(8)));
typedef float v4f __attribute__((ext_vector_type(4)));

__device__ __forceinline__ float fexp2(float x) {
#if __has_builtin(__builtin_amdgcn_exp2f)
    return __builtin_amdgcn_exp2f(x);
#else
    return exp2f(x);
#endif
}

union BFU { __hip_bfloat16 b; unsigned short u; };
__device__ __forceinline__ unsigned short f2bf(float f) { BFU x; x.b = __float2bfloat16(f); return x.u; }
__device__ __forceinline__ float bf2f(unsigned short u)  { BFU x; x.u = u; return __bfloat162float(x.b); }

// split f = hi + lo with hi,lo bf16; f - float(hi) is exact in fp32
__device__ __forceinline__ void split_bf16(float f, unsigned short& hi, unsigned short& lo) {
    hi = f2bf(f);
    lo = f2bf(f - bf2f(hi));
}

__device__ __forceinline__ void store8(unsigned short* dst, const unsigned short* s) {
    uint4 v;
    v.x = (unsigned)s[0] | ((unsigned)s[1] << 16);
    v.y = (unsigned)s[2] | ((unsigned)s[3] << 16);
    v.z = (unsigned)s[4] | ((unsigned)s[5] << 16);
    v.w = (unsigned)s[6] | ((unsigned)s[7] << 16);
    *reinterpret_cast<uint4*>(dst) = v;
}

// ---------------------------------------------------------------------------
// Prep (inversions only; 1024 threads): fp32 adjugate inverse of each
// covariance, 15 coeffs with k=-0.5*log2(e) folded, split hi/lo into compact
// B tables:
//   B1c = w_hi (decoder replicates to k16-31 => w_hi*(f_hi+f_lo))
//   B2c = w_lo (decoder zeroes k16-31      => w_lo*f_hi)
// Tile layout (per 16-gaussian tile t): uint4[32]: entry (quad*16 + col)
// holds B[k=quad*8..+7][n=col].
// ---------------------------------------------------------------------------
__global__ __launch_bounds__(256) void prep_kernel(
    const float*  __restrict__ means, // [M,4]
    const float*  __restrict__ covs,  // [M,4,4]
    unsigned short* __restrict__ Bt)  // 64 KB: B1c (32 KB) || B2c (32 KB)
{
    const int g = blockIdx.x * 256 + threadIdx.x;
    if (g >= M_GAUSS) return;

    const float4* C4 = reinterpret_cast<const float4*>(covs + 16 * g);
    const float4 r0 = C4[0], r1 = C4[1], r2 = C4[2], r3 = C4[3];
    const float a00=r0.x, a01=r0.y, a02=r0.z, a03=r0.w;
    const float a10=r1.x, a11=r1.y, a12=r1.z, a13=r1.w;
    const float a20=r2.x, a21=r2.y, a22=r2.z, a23=r2.w;
    const float a30=r3.x, a31=r3.y, a32=r3.z, a33=r3.w;

    const float s0=a00*a11-a01*a10, s1=a00*a12-a02*a10, s2=a00*a13-a03*a10;
    const float s3=a01*a12-a02*a11, s4=a01*a13-a03*a11, s5=a02*a13-a03*a12;
    const float c5=a22*a33-a23*a32, c4=a21*a33-a23*a31, c3=a21*a32-a22*a31;
    const float c2=a20*a33-a23*a30, c1=a20*a32-a22*a30, c0=a20*a31-a21*a30;
    const float det = s0*c5 - s1*c4 + s2*c3 + s3*c2 - s4*c1 + s5*c0;
    const float id  = 1.0f / det;

    const float b00=( a11*c5 - a12*c4 + a13*c3)*id;
    const float b01=(-a01*c5 + a02*c4 - a03*c3)*id;
    const float b10=(-a10*c5 + a12*c2 - a13*c1)*id;
    const float b11=( a00*c5 - a02*c2 + a03*c1)*id;
    const float b20=( a10*c4 - a11*c2 + a13*c0)*id;
    const float b21=(-a00*c4 + a01*c2 - a03*c0)*id;
    const float b30=(-a10*c3 + a11*c1 - a12*c0)*id;
    const float b31=( a00*c3 - a01*c1 + a02*c0)*id;
    const float b02=( a31*s5 - a32*s4 + a33*s3)*id;
    const float b03=(-a21*s5 + a22*s4 - a23*s3)*id;
    const float b12=(-a30*s5 + a32*s2 - a33*s1)*id;
    const float b13=( a20*s5 - a22*s2 + a23*s1)*id;
    const float b22=( a30*s4 - a31*s2 + a33*s0)*id;
    const float b23=(-a20*s4 + a21*s2 - a23*s0)*id;
    const float b32=(-a30*s3 + a31*s1 - a32*s0)*id;
    const float b33=( a20*s3 - a21*s1 + a22*s0)*id;

    const float m01=0.5f*(b01+b10), m02=0.5f*(b02+b20), m03=0.5f*(b03+b30);
    const float m12=0.5f*(b12+b21), m13=0.5f*(b13+b31), m23=0.5f*(b23+b32);

    const float4 mu = reinterpret_cast<const float4*>(means)[g];
    const float u0=mu.x, u1=mu.y, u2=mu.z, u3=mu.w;
    const float v0 = b00*u0 + m01*u1 + m02*u2 + m03*u3;
    const float v1 = m01*u0 + b11*u1 + m12*u2 + m13*u3;
    const float v2 = m02*u0 + m12*u1 + b22*u2 + m23*u3;
    const float v3 = m03*u0 + m13*u1 + m23*u2 + b33*u3;
    const float cc = u0*v0 + u1*v1 + u2*v2 + u3*v3;

    const float k  = -0.72134752044448170368f;   // -0.5 * log2(e)
    const float k2 = 2.0f * k;
    float w[16] = { k*b00,  k*b11,  k*b22,  k*b33,
                    k2*m01, k2*m02, k2*m03, k2*m12, k2*m13, k2*m23,
                    -k2*v0, -k2*v1, -k2*v2, -k2*v3, k*cc, 0.0f };
    unsigned short whi[16], wlo[16];
    #pragma unroll
    for (int q = 0; q < 16; ++q) split_bf16(w[q], whi[q], wlo[q]);

    const int t = g >> 4, cg = g & 15;
    unsigned short* b1 = Bt + (size_t)t * 32 * 8;                     // B1c
    store8(b1 + (0*16 + cg) * 8, whi + 0);   // quad 0: w_hi k0-7
    store8(b1 + (1*16 + cg) * 8, whi + 8);   // quad 1: w_hi k8-15
    unsigned short* b2 = Bt + (size_t)2048 * 8 + (size_t)t * 32 * 8;  // B2c
    store8(b2 + (0*16 + cg) * 8, wlo + 0);
    store8(b2 + (1*16 + cg) * 8, wlo + 8);
}

// ---------------------------------------------------------------------------
// Decoder (R6 structure; ONLY delta: A-fragments built in LDS from org/dir
// instead of read from a prep-written global table).
// 512 blocks x 512 threads (8 waves); block owns 64 rays (4 MFMA row-tiles),
// wave w sweeps gaussian tiles [8w, 8w+8). B tables (64 KB) staged to LDS
// once; A-table (4 KB) built by threads 0-63 in the shadow of the staging.
// Two MFMAs per row-tile per m-tile (split-bf16), epilogue
// acc += label*exp2(s). Cross-wave combine via disjoint per-wave LDS regions
// P[8][64][16] (32 KB, aliased onto the dead B region; A region untouched).
// ---------------------------------------------------------------------------
__global__ __launch_bounds__(512) void decoder_kernel(
    const float2* __restrict__ org,    // [N]
    const float2* __restrict__ dir,    // [N]
    const uint4* __restrict__ Btg,     // 64 KB B tables (B1c || B2c)
    const float* __restrict__ labels,  // [M]
    float*       __restrict__ out)     // [N]
{
    __shared__ uint4 lds[4096 + 256];  // 64 KB B (B1c [0,2048)|B2c [2048,4096)) + 4 KB A

    const int tid = threadIdx.x;
    const int L   = tid & 63;
    const int w   = tid >> 6;
    const int c15 = L & 15;
    const int q   = L >> 4;

    // stage B tables (linear copy, coalesced)
    #pragma unroll
    for (int i = 0; i < 8; ++i) lds[i * 512 + tid] = Btg[i * 512 + tid];

    // build A-fragment table for this block's 64 rays (threads 0-63):
    // MFMA A layout A[m=lane&15][k=quad*8+j]; k0-15 = f_hi, k16-31 = f_lo.
    if (tid < 64) {
        const int ray = blockIdx.x * 64 + tid;
        const float2 o = org[ray];
        const float2 d = dir[ray];
        const float p0 = o.x, p1 = o.y, p2 = d.x, p3 = d.y;
        float f[16] = { p0*p0, p1*p1, p2*p2, p3*p3,
                        p0*p1, p0*p2, p0*p3, p1*p2, p1*p3, p2*p3,
                        p0, p1, p2, p3, 1.0f, 0.0f };
        unsigned short hi[16], lo[16];
        #pragma unroll
        for (int k = 0; k < 16; ++k) split_bf16(f[k], hi[k], lo[k]);

        unsigned short* At = reinterpret_cast<unsigned short*>(lds + 4096);
        const int rt = tid >> 4, c = tid & 15;
        unsigned short* base = At + rt * 64 * 8;
        store8(base + (0*16 + c) * 8, hi + 0);   // quad 0: f_hi k0-7
        store8(base + (1*16 + c) * 8, hi + 8);   // quad 1: f_hi k8-15
        store8(base + (2*16 + c) * 8, lo + 0);   // quad 2: f_lo k0-7
        store8(base + (3*16 + c) * 8, lo + 8);   // quad 3: f_lo k8-15
    }
    __syncthreads();

    // A fragments: 4 row-tiles (64 rays) per block, held in registers
    v8s af[4];
    #pragma unroll
    for (int rt = 0; rt < 4; ++rt) {
        union { uint4 u; v8s s; } x;
        x.u = lds[4096 + rt * 64 + L];
        af[rt] = x.s;
    }

    v4f acc[4];
    #pragma unroll
    for (int rt = 0; rt < 4; ++rt) acc[rt] = (v4f){0.f, 0.f, 0.f, 0.f};

    const bool loHalf = (L < 32);
    #pragma unroll
    for (int i = 0; i < 8; ++i) {
        const int t = w * 8 + i;
        union { uint4 u; v8s s; } b1x, b2x;
        b1x.u = lds[t * 32 + (L & 31)];                 // [w_hi | w_hi]
        uint4 b2u = lds[2048 + t * 32 + (L & 31)];
        if (!loHalf) { b2u.x = 0; b2u.y = 0; b2u.z = 0; b2u.w = 0; }  // [w_lo | 0]
        b2x.u = b2u;
        const float lab = labels[t * 16 + c15];

        #pragma unroll
        for (int rt = 0; rt < 4; ++rt) {
            v4f cz = (v4f){0.f, 0.f, 0.f, 0.f};
            v4f s = __builtin_amdgcn_mfma_f32_16x16x32_bf16(af[rt], b2x.s, cz, 0, 0, 0);
            s = __builtin_amdgcn_mfma_f32_16x16x32_bf16(af[rt], b1x.s, s, 0, 0, 0);
            #pragma unroll
            for (int r = 0; r < 4; ++r)
                acc[rt][r] = fmaf(lab, fexp2(s[r]), acc[rt][r]);
        }
    }

    // ---- cross-wave combine: disjoint P[wave][ray][col], no atomics ----
    __syncthreads();                       // all B/A reads done; LDS reusable
    float* P = reinterpret_cast<float*>(lds);   // [8][64][16] = 32 KB
    #pragma unroll
    for (int rt = 0; rt < 4; ++rt) {
        #pragma unroll
        for (int r = 0; r < 4; ++r) {
            const int ray = rt * 16 + q * 4 + r;   // D row = quad*4 + reg
            P[(w << 10) + (ray << 4) + c15] = acc[rt][r];
        }
    }
    __syncthreads();

    if (tid < 64) {
        float tsum = 0.f;
        #pragma unroll
        for (int wv = 0; wv < 8; ++wv) {
            const float4* row = reinterpret_cast<const float4*>(P + (wv << 10) + (tid << 4));
            #pragma unroll
            for (int c4 = 0; c4 < 4; ++c4) {
                const float4 v = row[c4];
                tsum += (v.x + v.y) + (v.z + v.w);
            }
        }
        const float e = fexp2(-tsum * 1.4426950408889634f);
        out[blockIdx.x * 64 + tid] = 1.0f / (1.0f + e);
    }
}

extern "C" void kernel_launch(void* const* d_in, const int* in_sizes, int n_in,
                              void* d_out, int out_size, void* d_ws, size_t ws_size,
                              hipStream_t stream) {
    const float* origins    = (const float*)d_in[0];  // [N,2]
    const float* directions = (const float*)d_in[1];  // [N,2]
    const float* means      = (const float*)d_in[2];  // [M,4]
    const float* covs       = (const float*)d_in[3];  // [M,4,4]
    const float* labels     = (const float*)d_in[4];  // [M]
    float* out = (float*)d_out;

    unsigned short* Bt = (unsigned short*)d_ws;       // 64 KB compact B tables

    prep_kernel<<<dim3(M_GAUSS / 256), dim3(256), 0, stream>>>(means, covs, Bt);
    decoder_kernel<<<dim3(N_RAYS / 64), dim3(512), 0, stream>>>(
        (const float2*)origins, (const float2*)directions,
        (const uint4*)Bt, labels, out);
}